// Round 2
// baseline (113.111 us; speedup 1.0000x reference)
//
#include <hip/hip_runtime.h>

#define BATCH 8
#define NPTS 4096
#define KSEL 5          // K_NN; self-candidate excluded in-scan
#define ALPHA 1.05f
#define NSEG 16         // candidate-scan split per point (one wave each)
#define SEGLEN (NPTS / NSEG)   // 256
#define TPB (NSEG * 64)        // 1024 threads

// Non-negative IEEE floats order identically to their uint bit patterns.
static __device__ __forceinline__ unsigned min3u(unsigned a, unsigned b, unsigned c) {
  unsigned d;
  asm("v_min3_u32 %0, %1, %2, %3" : "=v"(d) : "v"(a), "v"(b), "v"(c));
  return d;
}
static __device__ __forceinline__ unsigned med3u(unsigned a, unsigned b, unsigned c) {
  unsigned d;
  asm("v_med3_u32 %0, %1, %2, %3" : "=v"(d) : "v"(a), "v"(b), "v"(c));
  return d;
}
static __device__ __forceinline__ unsigned max3u(unsigned a, unsigned b, unsigned c) {
  unsigned d;
  asm("v_max3_u32 %0, %1, %2, %3" : "=v"(d) : "v"(a), "v"(b), "v"(c));
  return d;
}
static __device__ __forceinline__ unsigned umn(unsigned a, unsigned b) { return a < b ? a : b; }
static __device__ __forceinline__ unsigned umx(unsigned a, unsigned b) { return a > b ? a : b; }

#define FINF 0x7F800000u   // +inf bit pattern

// Packed dual-FP32 (VOP3P). Each half is an IEEE f32 op with identical
// rounding to the scalar instruction -> bit-exact vs scalar sequence
// (absmax 0.0 verified R1).
typedef float v2f __attribute__((ext_vector_type(2)));

static __device__ __forceinline__ v2f pk_add(v2f a, v2f b) {
  v2f d;
  asm("v_pk_add_f32 %0, %1, %2" : "=v"(d) : "v"(a), "v"(b));
  return d;
}
static __device__ __forceinline__ v2f pk_mul(v2f a, v2f b) {
  v2f d;
  asm("v_pk_mul_f32 %0, %1, %2" : "=v"(d) : "v"(a), "v"(b));
  return d;
}
static __device__ __forceinline__ v2f pk_fma(v2f a, v2f b, v2f c) {
  v2f d;
  asm("v_pk_fma_f32 %0, %1, %2, %3" : "=v"(d) : "v"(a), "v"(b), "v"(c));
  return d;
}

// Fused branchless insert of two candidates into sorted m[0..KSEL-1].
static __device__ __forceinline__ void insert2(unsigned m[KSEL], unsigned tA, unsigned tB) {
#pragma unroll
  for (int k = 0; k < KSEL - 1; ++k) {
    const unsigned mk = m[k];
    m[k] = min3u(mk, tA, tB);
    const unsigned nA = med3u(mk, tA, tB);
    const unsigned nB = max3u(mk, tA, tB);
    tA = nA;
    tB = nB;
  }
  m[KSEL - 1] = min3u(m[KSEL - 1], tA, tB);
}

// ---------------------------------------------------------------------------
// Fast-path scan: candidates from GLOBAL SoA via float4 vector loads.
// R1 post-mortem: broadcast ds_read_b128 costs the same RF-return bandwidth as
// a gather (~12 cyc each on the single per-CU DS pipe) -> 6144 DS instrs/CU
// ~= 31 us, exposed once VALU work shrank. Global vector loads go through the
// TA/L1 path (separate pipe, ~4 cyc issue, L2-resident) and overlap under
// VALU. `zz` is an opaque zero VGPR: keeps the address formally divergent so
// the compiler emits global_load_dwordx4 into VGPRs (aligned pairs feed the
// pk asm directly) instead of scalarizing to s_load + s->v movs.
// ---------------------------------------------------------------------------
template <bool EXCL>
static __device__ __forceinline__ void scan_seg_g(const float4* __restrict__ xs4,
                                                  const float4* __restrict__ ys4,
                                                  const float4* __restrict__ zs4,
                                                  const int zz, const int j0, const int i,
                                                  const v2f nx2, const v2f ny2, const v2f nz2,
                                                  unsigned m[KSEL]) {
#pragma unroll 4
  for (int q = 0; q < SEGLEN / 4; ++q) {
    const float4 cx = xs4[q + zz];
    const float4 cy = ys4[q + zz];
    const float4 cz = zs4[q + zz];

    const v2f cxAB = {cx.x, cx.y}, cxCD = {cx.z, cx.w};
    const v2f cyAB = {cy.x, cy.y}, cyCD = {cy.z, cy.w};
    const v2f czAB = {cz.x, cz.y}, czCD = {cz.z, cz.w};

    const v2f dx0 = pk_add(cxAB, nx2);
    const v2f dx1 = pk_add(cxCD, nx2);
    const v2f dy0 = pk_add(cyAB, ny2);
    const v2f dy1 = pk_add(cyCD, ny2);
    const v2f dz0 = pk_add(czAB, nz2);
    const v2f dz1 = pk_add(czCD, nz2);

    v2f d0 = pk_mul(dx0, dx0);
    v2f d1 = pk_mul(dx1, dx1);
    d0 = pk_fma(dy0, dy0, d0);
    d1 = pk_fma(dy1, dy1, d1);
    d0 = pk_fma(dz0, dz0, d0);
    d1 = pk_fma(dz1, dz1, d1);

    unsigned uA = __float_as_uint(d0.x);
    unsigned uB = __float_as_uint(d0.y);
    unsigned uC = __float_as_uint(d1.x);
    unsigned uD = __float_as_uint(d1.y);
    if (EXCL) {
      const int jb = j0 + 4 * q;
      if (jb + 0 == i) uA = FINF;
      if (jb + 1 == i) uB = FINF;
      if (jb + 2 == i) uC = FINF;
      if (jb + 3 == i) uD = FINF;
    }

    insert2(m, uA, uB);
    insert2(m, uC, uD);
  }
}

// ---------------------------------------------------------------------------
// SoA transpose: pc [8][4096][3] -> xs/ys/zs [8*4096] in workspace.
// ~0.8 MB of traffic, runs once before the knn kernel. Also zeroes out[0].
// ---------------------------------------------------------------------------
__global__ __launch_bounds__(256) void soa_kernel(const float* __restrict__ pc,
                                                  float* __restrict__ xs,
                                                  float* __restrict__ ys,
                                                  float* __restrict__ zs,
                                                  float* __restrict__ out) {
  const int idx = blockIdx.x * 256 + threadIdx.x;  // 0..32767
  if (idx == 0) out[0] = 0.0f;
  const float x = pc[idx * 3 + 0];
  const float y = pc[idx * 3 + 1];
  const float z = pc[idx * 3 + 2];
  xs[idx] = x;
  ys[idx] = y;
  zs[idx] = z;
}

// ---------------------------------------------------------------------------
// Kernel 1 (fast path): per-point mean 5-NN squared distance.
// grid = 512 blocks, block = 1024 threads (16 waves). LDS = merge buffer only
// (20 KB). Candidates streamed from global SoA (see scan_seg_g).
// ---------------------------------------------------------------------------
__global__ __launch_bounds__(TPB) void knn_value_g(const float* __restrict__ xs,
                                                   const float* __restrict__ ys,
                                                   const float* __restrict__ zs,
                                                   float* __restrict__ value) {
  __shared__ unsigned cand[NSEG][64][KSEL];  // 20 KB

  const int tid = threadIdx.x;
  const int pt  = tid & 63;
  const int seg = __builtin_amdgcn_readfirstlane(tid >> 6);  // wave-uniform
  const int b    = blockIdx.x >> 6;
  const int tile = blockIdx.x & 63;
  const int i    = tile * 64 + pt;

  const float* __restrict__ xb = xs + b * NPTS;
  const float* __restrict__ yb = ys + b * NPTS;
  const float* __restrict__ zb = zs + b * NPTS;

  const float xi = xb[i];
  const float yi = yb[i];
  const float zi = zb[i];
  const v2f nx2 = {-xi, -xi};
  const v2f ny2 = {-yi, -yi};
  const v2f nz2 = {-zi, -zi};

  int zz;
  asm("v_mov_b32 %0, 0" : "=v"(zz));  // opaque zero (see scan_seg_g)

  unsigned m[KSEL];
#pragma unroll
  for (int k = 0; k < KSEL; ++k) m[k] = FINF;

  const int j0 = seg * SEGLEN;
  const float4* __restrict__ xs4 = (const float4*)(xb + j0);
  const float4* __restrict__ ys4 = (const float4*)(yb + j0);
  const float4* __restrict__ zs4 = (const float4*)(zb + j0);

  // Tile's own 64 indices all fall in segment tile>>2 (SEGLEN=256): only that
  // wave pays the self-exclusion compares.
  if (seg == (tile >> 2)) {
    scan_seg_g<true>(xs4, ys4, zs4, zz, j0, i, nx2, ny2, nz2, m);
  } else {
    scan_seg_g<false>(xs4, ys4, zs4, zz, j0, i, nx2, ny2, nz2, m);
  }

#pragma unroll
  for (int k = 0; k < KSEL; ++k) cand[seg][pt][k] = m[k];
  __syncthreads();

  // Tree-merge the 16 sorted lists per point: 8,4,2,1 pairwise merges.
  for (int st = 1; st < NSEG; st <<= 1) {
    const int pairs = NSEG / (2 * st);
    if (tid < pairs * 64) {
      const int q = tid >> 6;
      const int p = tid & 63;
      unsigned* A = &cand[2 * st * q][p][0];
      const unsigned* B = &cand[2 * st * q + st][p][0];
      unsigned mm[KSEL];
#pragma unroll
      for (int k = 0; k < KSEL; ++k) mm[k] = A[k];
#pragma unroll
      for (int k = 0; k < KSEL; ++k) {
        unsigned t = B[k];
#pragma unroll
        for (int u = 0; u < KSEL - 1; ++u) {
          const unsigned lo = umn(mm[u], t);
          t = umx(mm[u], t);
          mm[u] = lo;
        }
        mm[KSEL - 1] = umn(mm[KSEL - 1], t);
      }
#pragma unroll
      for (int k = 0; k < KSEL; ++k) A[k] = mm[k];
    }
    __syncthreads();
  }

  // Self excluded in-scan: mean of the 5 smallest, summed ascending.
  if (tid < 64) {
    float s5 = 0.f;
#pragma unroll
    for (int k = 0; k < KSEL; ++k) s5 += __uint_as_float(cand[0][tid][k]);
    value[b * NPTS + tile * 64 + tid] = s5 * 0.2f;
  }
}

// ---------------------------------------------------------------------------
// Fallback (ws too small for SoA): R1 kernel, LDS-staged candidates.
// ---------------------------------------------------------------------------
template <bool EXCL>
static __device__ __forceinline__ void scan_seg_l(const float* __restrict__ xs,
                                                  const float* __restrict__ ys,
                                                  const float* __restrict__ zs,
                                                  const int j0, const int i,
                                                  const v2f nx2, const v2f ny2, const v2f nz2,
                                                  unsigned m[KSEL]) {
#pragma unroll 4
  for (int jj = 0; jj < SEGLEN; jj += 4) {
    const float4 cx = *(const float4*)&xs[j0 + jj];
    const float4 cy = *(const float4*)&ys[j0 + jj];
    const float4 cz = *(const float4*)&zs[j0 + jj];

    const v2f cxAB = {cx.x, cx.y}, cxCD = {cx.z, cx.w};
    const v2f cyAB = {cy.x, cy.y}, cyCD = {cy.z, cy.w};
    const v2f czAB = {cz.x, cz.y}, czCD = {cz.z, cz.w};

    const v2f dx0 = pk_add(cxAB, nx2);
    const v2f dx1 = pk_add(cxCD, nx2);
    const v2f dy0 = pk_add(cyAB, ny2);
    const v2f dy1 = pk_add(cyCD, ny2);
    const v2f dz0 = pk_add(czAB, nz2);
    const v2f dz1 = pk_add(czCD, nz2);

    v2f d0 = pk_mul(dx0, dx0);
    v2f d1 = pk_mul(dx1, dx1);
    d0 = pk_fma(dy0, dy0, d0);
    d1 = pk_fma(dy1, dy1, d1);
    d0 = pk_fma(dz0, dz0, d0);
    d1 = pk_fma(dz1, dz1, d1);

    unsigned uA = __float_as_uint(d0.x);
    unsigned uB = __float_as_uint(d0.y);
    unsigned uC = __float_as_uint(d1.x);
    unsigned uD = __float_as_uint(d1.y);
    if (EXCL) {
      const int jb = j0 + jj;
      if (jb + 0 == i) uA = FINF;
      if (jb + 1 == i) uB = FINF;
      if (jb + 2 == i) uC = FINF;
      if (jb + 3 == i) uD = FINF;
    }

    insert2(m, uA, uB);
    insert2(m, uC, uD);
  }
}

__global__ __launch_bounds__(TPB) void knn_value_lds(const float* __restrict__ pc,
                                                     float* __restrict__ value,
                                                     float* __restrict__ out) {
  __shared__ union __align__(16) {
    struct { float xs[NPTS]; float ys[NPTS]; float zs[NPTS]; } s;  // 48 KB
    unsigned cand[NSEG][64][KSEL];                                 // 20 KB
  } sh;

  const int tid = threadIdx.x;
  const int pt  = tid & 63;
  const int seg = __builtin_amdgcn_readfirstlane(tid >> 6);
  const int b    = blockIdx.x >> 6;
  const int tile = blockIdx.x & 63;
  const int i    = tile * 64 + pt;

  if (blockIdx.x == 0 && tid == 0) out[0] = 0.0f;

  const float* __restrict__ base = pc + (size_t)b * (NPTS * 3);

#pragma unroll
  for (int p = 0; p < NPTS / TPB; ++p) {
    const int idx = tid + p * TPB;
    sh.s.xs[idx] = base[idx * 3 + 0];
    sh.s.ys[idx] = base[idx * 3 + 1];
    sh.s.zs[idx] = base[idx * 3 + 2];
  }
  __syncthreads();

  const float xi = sh.s.xs[i];
  const float yi = sh.s.ys[i];
  const float zi = sh.s.zs[i];
  const v2f nx2 = {-xi, -xi};
  const v2f ny2 = {-yi, -yi};
  const v2f nz2 = {-zi, -zi};

  unsigned m[KSEL];
#pragma unroll
  for (int k = 0; k < KSEL; ++k) m[k] = FINF;

  const int j0 = seg * SEGLEN;
  if (seg == (tile >> 2)) {
    scan_seg_l<true>(sh.s.xs, sh.s.ys, sh.s.zs, j0, i, nx2, ny2, nz2, m);
  } else {
    scan_seg_l<false>(sh.s.xs, sh.s.ys, sh.s.zs, j0, i, nx2, ny2, nz2, m);
  }
  __syncthreads();

#pragma unroll
  for (int k = 0; k < KSEL; ++k) sh.cand[seg][pt][k] = m[k];
  __syncthreads();

  for (int st = 1; st < NSEG; st <<= 1) {
    const int pairs = NSEG / (2 * st);
    if (tid < pairs * 64) {
      const int q = tid >> 6;
      const int p = tid & 63;
      unsigned* A = &sh.cand[2 * st * q][p][0];
      const unsigned* B = &sh.cand[2 * st * q + st][p][0];
      unsigned mm[KSEL];
#pragma unroll
      for (int k = 0; k < KSEL; ++k) mm[k] = A[k];
#pragma unroll
      for (int k = 0; k < KSEL; ++k) {
        unsigned t = B[k];
#pragma unroll
        for (int u = 0; u < KSEL - 1; ++u) {
          const unsigned lo = umn(mm[u], t);
          t = umx(mm[u], t);
          mm[u] = lo;
        }
        mm[KSEL - 1] = umn(mm[KSEL - 1], t);
      }
#pragma unroll
      for (int k = 0; k < KSEL; ++k) A[k] = mm[k];
    }
    __syncthreads();
  }

  if (tid < 64) {
    float s5 = 0.f;
#pragma unroll
    for (int k = 0; k < KSEL; ++k) s5 += __uint_as_float(sh.cand[0][tid][k]);
    value[b * NPTS + tile * 64 + tid] = s5 * 0.2f;
  }
}

// ---------------------------------------------------------------------------
// Kernel 2: per-batch stats + masked mean * weight -> atomicAdd into out.
// UNCHANGED (bit-exact output).
// ---------------------------------------------------------------------------
__global__ __launch_bounds__(256) void stats_kernel(const float* __restrict__ value,
                                                    const float* __restrict__ weights,
                                                    float* __restrict__ out) {
  __shared__ float red[256];
  const int b   = blockIdx.x;
  const int tid = threadIdx.x;
  const float* __restrict__ v = value + b * NPTS;

  float s = 0.f;
  for (int j = tid; j < NPTS; j += 256) s += v[j];
  red[tid] = s;
  __syncthreads();
  for (int off = 128; off > 0; off >>= 1) {
    if (tid < off) red[tid] += red[tid + off];
    __syncthreads();
  }
  const float mean = red[0] * (1.0f / NPTS);
  __syncthreads();

  float s2 = 0.f;
  for (int j = tid; j < NPTS; j += 256) {
    const float d = v[j] - mean;
    s2 += d * d;
  }
  red[tid] = s2;
  __syncthreads();
  for (int off = 128; off > 0; off >>= 1) {
    if (tid < off) red[tid] += red[tid + off];
    __syncthreads();
  }
  const float thr = mean + ALPHA * sqrtf(red[0] * (1.0f / (NPTS - 1)));
  __syncthreads();

  float s3 = 0.f;
  for (int j = tid; j < NPTS; j += 256) {
    const float vv = v[j];
    if (vv > thr) s3 += vv;
  }
  red[tid] = s3;
  __syncthreads();
  for (int off = 128; off > 0; off >>= 1) {
    if (tid < off) red[tid] += red[tid + off];
    __syncthreads();
  }
  if (tid == 0) {
    atomicAdd(out, red[0] * (1.0f / NPTS) * weights[b] * (1.0f / BATCH));
  }
}

extern "C" void kernel_launch(void* const* d_in, const int* in_sizes, int n_in,
                              void* d_out, int out_size, void* d_ws, size_t ws_size,
                              hipStream_t stream) {
  const float* pc      = (const float*)d_in[0];   // [8,4096,3] f32
  const float* weights = (const float*)d_in[1];   // [8] f32
  float* out   = (float*)d_out;                   // scalar f32
  float* wsf   = (float*)d_ws;

  const size_t NB = (size_t)BATCH * NPTS;         // 32768
  const size_t need = NB * 4 * sizeof(float);     // value + xs + ys + zs = 512 KB

  if (ws_size >= need) {
    float* value = wsf;
    float* xs = wsf + NB;
    float* ys = wsf + 2 * NB;
    float* zs = wsf + 3 * NB;
    soa_kernel<<<dim3(BATCH * NPTS / 256), dim3(256), 0, stream>>>(pc, xs, ys, zs, out);
    knn_value_g<<<dim3(BATCH * (NPTS / 64)), dim3(TPB), 0, stream>>>(xs, ys, zs, value);
    stats_kernel<<<dim3(BATCH), dim3(256), 0, stream>>>(value, weights, out);
  } else {
    float* value = wsf;                           // 128 KB (R1 layout)
    knn_value_lds<<<dim3(BATCH * (NPTS / 64)), dim3(TPB), 0, stream>>>(pc, value, out);
    stats_kernel<<<dim3(BATCH), dim3(256), 0, stream>>>(value, weights, out);
  }
}

// Round 3
// 104.569 us; speedup vs baseline: 1.0817x; 1.0817x over previous
//
#include <hip/hip_runtime.h>

#define BATCH 8
#define NPTS 4096
#define KSEL 5          // K_NN; self-candidate excluded in-scan
#define ALPHA 1.05f
#define NSEG 16         // candidate-scan split per point (one wave each)
#define SEGLEN (NPTS / NSEG)   // 256
#define TPB (NSEG * 64)        // 1024 threads

// Non-negative IEEE floats order identically to their uint bit patterns.
static __device__ __forceinline__ unsigned min3u(unsigned a, unsigned b, unsigned c) {
  unsigned d;
  asm("v_min3_u32 %0, %1, %2, %3" : "=v"(d) : "v"(a), "v"(b), "v"(c));
  return d;
}
static __device__ __forceinline__ unsigned med3u(unsigned a, unsigned b, unsigned c) {
  unsigned d;
  asm("v_med3_u32 %0, %1, %2, %3" : "=v"(d) : "v"(a), "v"(b), "v"(c));
  return d;
}
static __device__ __forceinline__ unsigned max3u(unsigned a, unsigned b, unsigned c) {
  unsigned d;
  asm("v_max3_u32 %0, %1, %2, %3" : "=v"(d) : "v"(a), "v"(b), "v"(c));
  return d;
}
static __device__ __forceinline__ unsigned umn(unsigned a, unsigned b) { return a < b ? a : b; }
static __device__ __forceinline__ unsigned umx(unsigned a, unsigned b) { return a > b ? a : b; }

#define FINF 0x7F800000u   // +inf bit pattern

// Packed dual-FP32 (VOP3P). Each half is an IEEE f32 op with identical
// rounding to the scalar instruction -> bit-exact vs scalar sequence
// (absmax 0.0 verified R1/R2).
typedef float v2f __attribute__((ext_vector_type(2)));

// All-VGPR variants (LDS fallback path).
static __device__ __forceinline__ v2f pk_add(v2f a, v2f b) {
  v2f d;
  asm("v_pk_add_f32 %0, %1, %2" : "=v"(d) : "v"(a), "v"(b));
  return d;
}
static __device__ __forceinline__ v2f pk_mul(v2f a, v2f b) {
  v2f d;
  asm("v_pk_mul_f32 %0, %1, %2" : "=v"(d) : "v"(a), "v"(b));
  return d;
}
static __device__ __forceinline__ v2f pk_fma(v2f a, v2f b, v2f c) {
  v2f d;
  asm("v_pk_fma_f32 %0, %1, %2, %3" : "=v"(d) : "v"(a), "v"(b), "v"(c));
  return d;
}
// Candidate operand in SGPR pair (src0), per-point operand in VGPR pair.
// VOP3P permits one SGPR(-pair) source -> zero s->v movs on the hot path.
static __device__ __forceinline__ v2f pk_add_sv(v2f s, v2f v) {
  v2f d;
  asm("v_pk_add_f32 %0, %1, %2" : "=v"(d) : "s"(s), "v"(v));
  return d;
}

// Fused branchless insert of two candidates into sorted m[0..KSEL-1].
static __device__ __forceinline__ void insert2(unsigned m[KSEL], unsigned tA, unsigned tB) {
#pragma unroll
  for (int k = 0; k < KSEL - 1; ++k) {
    const unsigned mk = m[k];
    m[k] = min3u(mk, tA, tB);
    const unsigned nA = med3u(mk, tA, tB);
    const unsigned nB = max3u(mk, tA, tB);
    tA = nA;
    tB = nB;
  }
  m[KSEL - 1] = min3u(m[KSEL - 1], tA, tB);
}

// ---------------------------------------------------------------------------
// Fast-path scan: candidates via SCALAR loads (s_load_dwordx4) from global
// SoA. R2 post-mortem: wave-uniform candidate data belongs in SGPRs — SMEM
// rides the scalar pipe (off VALU/VMEM), needs no per-lane address math, and
// the SoA float4 sub-pairs feed v_pk_*_f32 src0 directly. The compiler
// already wanted to scalarize these loads (R2 needed an opaque index to stop
// it); here we let it. unroll 4 puts 12 s_loads in flight per 16 candidates.
// ---------------------------------------------------------------------------
template <bool EXCL>
static __device__ __forceinline__ void scan_seg_s(const float4* __restrict__ xs4,
                                                  const float4* __restrict__ ys4,
                                                  const float4* __restrict__ zs4,
                                                  const int j0, const int i,
                                                  const v2f nx2, const v2f ny2, const v2f nz2,
                                                  unsigned m[KSEL]) {
#pragma unroll 4
  for (int q = 0; q < SEGLEN / 4; ++q) {
    const float4 cx = xs4[q];   // uniform address -> s_load_dwordx4 (SGPRs)
    const float4 cy = ys4[q];
    const float4 cz = zs4[q];

    const v2f cxAB = {cx.x, cx.y}, cxCD = {cx.z, cx.w};  // SGPR pairs
    const v2f cyAB = {cy.x, cy.y}, cyCD = {cy.z, cy.w};
    const v2f czAB = {cz.x, cz.y}, czCD = {cz.z, cz.w};

    const v2f dx0 = pk_add_sv(cxAB, nx2);
    const v2f dx1 = pk_add_sv(cxCD, nx2);
    const v2f dy0 = pk_add_sv(cyAB, ny2);
    const v2f dy1 = pk_add_sv(cyCD, ny2);
    const v2f dz0 = pk_add_sv(czAB, nz2);
    const v2f dz1 = pk_add_sv(czCD, nz2);

    v2f d0 = pk_mul(dx0, dx0);
    v2f d1 = pk_mul(dx1, dx1);
    d0 = pk_fma(dy0, dy0, d0);
    d1 = pk_fma(dy1, dy1, d1);
    d0 = pk_fma(dz0, dz0, d0);
    d1 = pk_fma(dz1, dz1, d1);

    unsigned uA = __float_as_uint(d0.x);
    unsigned uB = __float_as_uint(d0.y);
    unsigned uC = __float_as_uint(d1.x);
    unsigned uD = __float_as_uint(d1.y);
    if (EXCL) {
      const int jb = j0 + 4 * q;
      if (jb + 0 == i) uA = FINF;
      if (jb + 1 == i) uB = FINF;
      if (jb + 2 == i) uC = FINF;
      if (jb + 3 == i) uD = FINF;
    }

    insert2(m, uA, uB);
    insert2(m, uC, uD);
  }
}

// ---------------------------------------------------------------------------
// SoA transpose: pc [8][4096][3] -> xs/ys/zs [8*4096] in workspace.
// Runs once before the knn kernel. Also zeroes out[0].
// ---------------------------------------------------------------------------
__global__ __launch_bounds__(256) void soa_kernel(const float* __restrict__ pc,
                                                  float* __restrict__ xs,
                                                  float* __restrict__ ys,
                                                  float* __restrict__ zs,
                                                  float* __restrict__ out) {
  const int idx = blockIdx.x * 256 + threadIdx.x;  // 0..32767
  if (idx == 0) out[0] = 0.0f;
  const float x = pc[idx * 3 + 0];
  const float y = pc[idx * 3 + 1];
  const float z = pc[idx * 3 + 2];
  xs[idx] = x;
  ys[idx] = y;
  zs[idx] = z;
}

// ---------------------------------------------------------------------------
// Kernel 1 (fast path): per-point mean 5-NN squared distance.
// grid = 512 blocks, block = 1024 threads (16 waves). LDS = merge buffer only
// (20 KB). Candidates streamed via SMEM (see scan_seg_s).
// ---------------------------------------------------------------------------
__global__ __launch_bounds__(TPB) void knn_value_s(const float* __restrict__ xs,
                                                   const float* __restrict__ ys,
                                                   const float* __restrict__ zs,
                                                   float* __restrict__ value) {
  __shared__ unsigned cand[NSEG][64][KSEL];  // 20 KB

  const int tid = threadIdx.x;
  const int pt  = tid & 63;
  const int seg = __builtin_amdgcn_readfirstlane(tid >> 6);  // wave-uniform
  const int b    = blockIdx.x >> 6;
  const int tile = blockIdx.x & 63;
  const int i    = tile * 64 + pt;

  const float* __restrict__ xb = xs + b * NPTS;
  const float* __restrict__ yb = ys + b * NPTS;
  const float* __restrict__ zb = zs + b * NPTS;

  const float xi = xb[i];
  const float yi = yb[i];
  const float zi = zb[i];
  const v2f nx2 = {-xi, -xi};
  const v2f ny2 = {-yi, -yi};
  const v2f nz2 = {-zi, -zi};

  unsigned m[KSEL];
#pragma unroll
  for (int k = 0; k < KSEL; ++k) m[k] = FINF;

  const int j0 = seg * SEGLEN;
  const float4* __restrict__ xs4 = (const float4*)(xb + j0);
  const float4* __restrict__ ys4 = (const float4*)(yb + j0);
  const float4* __restrict__ zs4 = (const float4*)(zb + j0);

  // Tile's own 64 indices all fall in segment tile>>2 (SEGLEN=256): only that
  // wave pays the self-exclusion compares.
  if (seg == (tile >> 2)) {
    scan_seg_s<true>(xs4, ys4, zs4, j0, i, nx2, ny2, nz2, m);
  } else {
    scan_seg_s<false>(xs4, ys4, zs4, j0, i, nx2, ny2, nz2, m);
  }

#pragma unroll
  for (int k = 0; k < KSEL; ++k) cand[seg][pt][k] = m[k];
  __syncthreads();

  // Tree-merge the 16 sorted lists per point: 8,4,2,1 pairwise merges.
  for (int st = 1; st < NSEG; st <<= 1) {
    const int pairs = NSEG / (2 * st);
    if (tid < pairs * 64) {
      const int q = tid >> 6;
      const int p = tid & 63;
      unsigned* A = &cand[2 * st * q][p][0];
      const unsigned* B = &cand[2 * st * q + st][p][0];
      unsigned mm[KSEL];
#pragma unroll
      for (int k = 0; k < KSEL; ++k) mm[k] = A[k];
#pragma unroll
      for (int k = 0; k < KSEL; ++k) {
        unsigned t = B[k];
#pragma unroll
        for (int u = 0; u < KSEL - 1; ++u) {
          const unsigned lo = umn(mm[u], t);
          t = umx(mm[u], t);
          mm[u] = lo;
        }
        mm[KSEL - 1] = umn(mm[KSEL - 1], t);
      }
#pragma unroll
      for (int k = 0; k < KSEL; ++k) A[k] = mm[k];
    }
    __syncthreads();
  }

  // Self excluded in-scan: mean of the 5 smallest, summed ascending.
  if (tid < 64) {
    float s5 = 0.f;
#pragma unroll
    for (int k = 0; k < KSEL; ++k) s5 += __uint_as_float(cand[0][tid][k]);
    value[b * NPTS + tile * 64 + tid] = s5 * 0.2f;
  }
}

// ---------------------------------------------------------------------------
// Fallback (ws too small for SoA): R1 kernel, LDS-staged candidates.
// ---------------------------------------------------------------------------
template <bool EXCL>
static __device__ __forceinline__ void scan_seg_l(const float* __restrict__ xs,
                                                  const float* __restrict__ ys,
                                                  const float* __restrict__ zs,
                                                  const int j0, const int i,
                                                  const v2f nx2, const v2f ny2, const v2f nz2,
                                                  unsigned m[KSEL]) {
#pragma unroll 4
  for (int jj = 0; jj < SEGLEN; jj += 4) {
    const float4 cx = *(const float4*)&xs[j0 + jj];
    const float4 cy = *(const float4*)&ys[j0 + jj];
    const float4 cz = *(const float4*)&zs[j0 + jj];

    const v2f cxAB = {cx.x, cx.y}, cxCD = {cx.z, cx.w};
    const v2f cyAB = {cy.x, cy.y}, cyCD = {cy.z, cy.w};
    const v2f czAB = {cz.x, cz.y}, czCD = {cz.z, cz.w};

    const v2f dx0 = pk_add(cxAB, nx2);
    const v2f dx1 = pk_add(cxCD, nx2);
    const v2f dy0 = pk_add(cyAB, ny2);
    const v2f dy1 = pk_add(cyCD, ny2);
    const v2f dz0 = pk_add(czAB, nz2);
    const v2f dz1 = pk_add(czCD, nz2);

    v2f d0 = pk_mul(dx0, dx0);
    v2f d1 = pk_mul(dx1, dx1);
    d0 = pk_fma(dy0, dy0, d0);
    d1 = pk_fma(dy1, dy1, d1);
    d0 = pk_fma(dz0, dz0, d0);
    d1 = pk_fma(dz1, dz1, d1);

    unsigned uA = __float_as_uint(d0.x);
    unsigned uB = __float_as_uint(d0.y);
    unsigned uC = __float_as_uint(d1.x);
    unsigned uD = __float_as_uint(d1.y);
    if (EXCL) {
      const int jb = j0 + jj;
      if (jb + 0 == i) uA = FINF;
      if (jb + 1 == i) uB = FINF;
      if (jb + 2 == i) uC = FINF;
      if (jb + 3 == i) uD = FINF;
    }

    insert2(m, uA, uB);
    insert2(m, uC, uD);
  }
}

__global__ __launch_bounds__(TPB) void knn_value_lds(const float* __restrict__ pc,
                                                     float* __restrict__ value,
                                                     float* __restrict__ out) {
  __shared__ union __align__(16) {
    struct { float xs[NPTS]; float ys[NPTS]; float zs[NPTS]; } s;  // 48 KB
    unsigned cand[NSEG][64][KSEL];                                 // 20 KB
  } sh;

  const int tid = threadIdx.x;
  const int pt  = tid & 63;
  const int seg = __builtin_amdgcn_readfirstlane(tid >> 6);
  const int b    = blockIdx.x >> 6;
  const int tile = blockIdx.x & 63;
  const int i    = tile * 64 + pt;

  if (blockIdx.x == 0 && tid == 0) out[0] = 0.0f;

  const float* __restrict__ base = pc + (size_t)b * (NPTS * 3);

#pragma unroll
  for (int p = 0; p < NPTS / TPB; ++p) {
    const int idx = tid + p * TPB;
    sh.s.xs[idx] = base[idx * 3 + 0];
    sh.s.ys[idx] = base[idx * 3 + 1];
    sh.s.zs[idx] = base[idx * 3 + 2];
  }
  __syncthreads();

  const float xi = sh.s.xs[i];
  const float yi = sh.s.ys[i];
  const float zi = sh.s.zs[i];
  const v2f nx2 = {-xi, -xi};
  const v2f ny2 = {-yi, -yi};
  const v2f nz2 = {-zi, -zi};

  unsigned m[KSEL];
#pragma unroll
  for (int k = 0; k < KSEL; ++k) m[k] = FINF;

  const int j0 = seg * SEGLEN;
  if (seg == (tile >> 2)) {
    scan_seg_l<true>(sh.s.xs, sh.s.ys, sh.s.zs, j0, i, nx2, ny2, nz2, m);
  } else {
    scan_seg_l<false>(sh.s.xs, sh.s.ys, sh.s.zs, j0, i, nx2, ny2, nz2, m);
  }
  __syncthreads();

#pragma unroll
  for (int k = 0; k < KSEL; ++k) sh.cand[seg][pt][k] = m[k];
  __syncthreads();

  for (int st = 1; st < NSEG; st <<= 1) {
    const int pairs = NSEG / (2 * st);
    if (tid < pairs * 64) {
      const int q = tid >> 6;
      const int p = tid & 63;
      unsigned* A = &sh.cand[2 * st * q][p][0];
      const unsigned* B = &sh.cand[2 * st * q + st][p][0];
      unsigned mm[KSEL];
#pragma unroll
      for (int k = 0; k < KSEL; ++k) mm[k] = A[k];
#pragma unroll
      for (int k = 0; k < KSEL; ++k) {
        unsigned t = B[k];
#pragma unroll
        for (int u = 0; u < KSEL - 1; ++u) {
          const unsigned lo = umn(mm[u], t);
          t = umx(mm[u], t);
          mm[u] = lo;
        }
        mm[KSEL - 1] = umn(mm[KSEL - 1], t);
      }
#pragma unroll
      for (int k = 0; k < KSEL; ++k) A[k] = mm[k];
    }
    __syncthreads();
  }

  if (tid < 64) {
    float s5 = 0.f;
#pragma unroll
    for (int k = 0; k < KSEL; ++k) s5 += __uint_as_float(sh.cand[0][tid][k]);
    value[b * NPTS + tile * 64 + tid] = s5 * 0.2f;
  }
}

// ---------------------------------------------------------------------------
// Kernel 2: per-batch stats + masked mean * weight -> atomicAdd into out.
// UNCHANGED (bit-exact output).
// ---------------------------------------------------------------------------
__global__ __launch_bounds__(256) void stats_kernel(const float* __restrict__ value,
                                                    const float* __restrict__ weights,
                                                    float* __restrict__ out) {
  __shared__ float red[256];
  const int b   = blockIdx.x;
  const int tid = threadIdx.x;
  const float* __restrict__ v = value + b * NPTS;

  float s = 0.f;
  for (int j = tid; j < NPTS; j += 256) s += v[j];
  red[tid] = s;
  __syncthreads();
  for (int off = 128; off > 0; off >>= 1) {
    if (tid < off) red[tid] += red[tid + off];
    __syncthreads();
  }
  const float mean = red[0] * (1.0f / NPTS);
  __syncthreads();

  float s2 = 0.f;
  for (int j = tid; j < NPTS; j += 256) {
    const float d = v[j] - mean;
    s2 += d * d;
  }
  red[tid] = s2;
  __syncthreads();
  for (int off = 128; off > 0; off >>= 1) {
    if (tid < off) red[tid] += red[tid + off];
    __syncthreads();
  }
  const float thr = mean + ALPHA * sqrtf(red[0] * (1.0f / (NPTS - 1)));
  __syncthreads();

  float s3 = 0.f;
  for (int j = tid; j < NPTS; j += 256) {
    const float vv = v[j];
    if (vv > thr) s3 += vv;
  }
  red[tid] = s3;
  __syncthreads();
  for (int off = 128; off > 0; off >>= 1) {
    if (tid < off) red[tid] += red[tid + off];
    __syncthreads();
  }
  if (tid == 0) {
    atomicAdd(out, red[0] * (1.0f / NPTS) * weights[b] * (1.0f / BATCH));
  }
}

extern "C" void kernel_launch(void* const* d_in, const int* in_sizes, int n_in,
                              void* d_out, int out_size, void* d_ws, size_t ws_size,
                              hipStream_t stream) {
  const float* pc      = (const float*)d_in[0];   // [8,4096,3] f32
  const float* weights = (const float*)d_in[1];   // [8] f32
  float* out   = (float*)d_out;                   // scalar f32
  float* wsf   = (float*)d_ws;

  const size_t NB = (size_t)BATCH * NPTS;         // 32768
  const size_t need = NB * 4 * sizeof(float);     // value + xs + ys + zs = 512 KB

  if (ws_size >= need) {
    float* value = wsf;
    float* xs = wsf + NB;
    float* ys = wsf + 2 * NB;
    float* zs = wsf + 3 * NB;
    soa_kernel<<<dim3(BATCH * NPTS / 256), dim3(256), 0, stream>>>(pc, xs, ys, zs, out);
    knn_value_s<<<dim3(BATCH * (NPTS / 64)), dim3(TPB), 0, stream>>>(xs, ys, zs, value);
    stats_kernel<<<dim3(BATCH), dim3(256), 0, stream>>>(value, weights, out);
  } else {
    float* value = wsf;                           // 128 KB (R1 layout)
    knn_value_lds<<<dim3(BATCH * (NPTS / 64)), dim3(TPB), 0, stream>>>(pc, value, out);
    stats_kernel<<<dim3(BATCH), dim3(256), 0, stream>>>(value, weights, out);
  }
}

// Round 4
// 100.764 us; speedup vs baseline: 1.1225x; 1.0378x over previous
//
#include <hip/hip_runtime.h>

#define BATCH 8
#define NPTS 4096
#define KSEL 5          // K_NN; self-candidate excluded in-scan
#define ALPHA 1.05f
#define NSEG 16         // candidate-scan split per point (one wave each)
#define SEGLEN (NPTS / NSEG)   // 256
#define TPB (NSEG * 64)        // 1024 threads

// Non-negative IEEE floats order identically to their uint bit patterns.
static __device__ __forceinline__ unsigned min3u(unsigned a, unsigned b, unsigned c) {
  unsigned d;
  asm("v_min3_u32 %0, %1, %2, %3" : "=v"(d) : "v"(a), "v"(b), "v"(c));
  return d;
}
static __device__ __forceinline__ unsigned med3u(unsigned a, unsigned b, unsigned c) {
  unsigned d;
  asm("v_med3_u32 %0, %1, %2, %3" : "=v"(d) : "v"(a), "v"(b), "v"(c));
  return d;
}
static __device__ __forceinline__ unsigned max3u(unsigned a, unsigned b, unsigned c) {
  unsigned d;
  asm("v_max3_u32 %0, %1, %2, %3" : "=v"(d) : "v"(a), "v"(b), "v"(c));
  return d;
}
static __device__ __forceinline__ unsigned umn(unsigned a, unsigned b) { return a < b ? a : b; }
static __device__ __forceinline__ unsigned umx(unsigned a, unsigned b) { return a > b ? a : b; }

#define FINF 0x7F800000u   // +inf bit pattern

// Packed dual-FP32 (fallback kernel only). R3 post-mortem: v_pk_*_f32 on
// CDNA4 is an instruction-density feature, NOT extra throughput (157.3 TF
// spec == the scalar rate; pk takes >=2x cycles/instr) — hot path is scalar.
typedef float v2f __attribute__((ext_vector_type(2)));

static __device__ __forceinline__ v2f pk_add(v2f a, v2f b) {
  v2f d;
  asm("v_pk_add_f32 %0, %1, %2" : "=v"(d) : "v"(a), "v"(b));
  return d;
}
static __device__ __forceinline__ v2f pk_mul(v2f a, v2f b) {
  v2f d;
  asm("v_pk_mul_f32 %0, %1, %2" : "=v"(d) : "v"(a), "v"(b));
  return d;
}
static __device__ __forceinline__ v2f pk_fma(v2f a, v2f b, v2f c) {
  v2f d;
  asm("v_pk_fma_f32 %0, %1, %2, %3" : "=v"(d) : "v"(a), "v"(b), "v"(c));
  return d;
}

// Fused branchless insert of two candidates into sorted m[0..KSEL-1].
static __device__ __forceinline__ void insert2(unsigned m[KSEL], unsigned tA, unsigned tB) {
#pragma unroll
  for (int k = 0; k < KSEL - 1; ++k) {
    const unsigned mk = m[k];
    m[k] = min3u(mk, tA, tB);
    const unsigned nA = med3u(mk, tA, tB);
    const unsigned nB = max3u(mk, tA, tB);
    tA = nA;
    tB = nB;
  }
  m[KSEL - 1] = min3u(m[KSEL - 1], tA, tB);
}

// ---------------------------------------------------------------------------
// Fast-path scan: candidates via s_load_dwordx4 (wave-uniform SoA -> SGPRs,
// proven R3: SGPR pipe, no per-lane addresses). Changes vs R3:
//  * distance math in plain scalar C: v_sub_f32 folds the SGPR candidate as
//    src0 (no movs), scalar rate == pk rate on CDNA4 but half-or-quarter the
//    cycles per group, and normal IR lets the scheduler interleave dist with
//    the selection network instead of stalling on opaque inline-asm chains.
//  * explicit depth-2 prefetch: group q consumes registers loaded at q-2, so
//    ~200-cycle SMEM latency hides under ~2 groups of compute.
// (x_j - x_i)^2 is bit-identical to the R1-R3 pk form (sign-symmetric).
// ---------------------------------------------------------------------------
template <bool EXCL>
static __device__ __forceinline__ void scan_seg_sc(const float4* __restrict__ xs4,
                                                   const float4* __restrict__ ys4,
                                                   const float4* __restrict__ zs4,
                                                   const int j0, const int i,
                                                   const float xi, const float yi, const float zi,
                                                   unsigned m[KSEL]) {
  const int NG = SEGLEN / 4;  // 64 groups of 4 candidates
  float4 a0x = xs4[0], a0y = ys4[0], a0z = zs4[0];
  float4 a1x = xs4[1], a1y = ys4[1], a1z = zs4[1];
#pragma unroll 4
  for (int q = 0; q < NG; ++q) {
    const float4 cx = a0x, cy = a0y, cz = a0z;
    a0x = a1x; a0y = a1y; a0z = a1z;
    const int qn = (q + 2 < NG) ? (q + 2) : (NG - 1);  // clamped tail (stay in bounds)
    a1x = xs4[qn]; a1y = ys4[qn]; a1z = zs4[qn];

    const float dxA = cx.x - xi, dyA = cy.x - yi, dzA = cz.x - zi;
    const float dxB = cx.y - xi, dyB = cy.y - yi, dzB = cz.y - zi;
    const float dxC = cx.z - xi, dyC = cy.z - yi, dzC = cz.z - zi;
    const float dxD = cx.w - xi, dyD = cy.w - yi, dzD = cz.w - zi;

    float dA = dxA * dxA, dB = dxB * dxB, dC = dxC * dxC, dD = dxD * dxD;
    dA = fmaf(dyA, dyA, dA);
    dB = fmaf(dyB, dyB, dB);
    dC = fmaf(dyC, dyC, dC);
    dD = fmaf(dyD, dyD, dD);
    dA = fmaf(dzA, dzA, dA);
    dB = fmaf(dzB, dzB, dB);
    dC = fmaf(dzC, dzC, dC);
    dD = fmaf(dzD, dzD, dD);

    unsigned uA = __float_as_uint(dA);
    unsigned uB = __float_as_uint(dB);
    unsigned uC = __float_as_uint(dC);
    unsigned uD = __float_as_uint(dD);
    if (EXCL) {
      const int jb = j0 + 4 * q;
      if (jb + 0 == i) uA = FINF;
      if (jb + 1 == i) uB = FINF;
      if (jb + 2 == i) uC = FINF;
      if (jb + 3 == i) uD = FINF;
    }

    insert2(m, uA, uB);
    insert2(m, uC, uD);
  }
}

// ---------------------------------------------------------------------------
// SoA transpose: pc [8][4096][3] -> xs/ys/zs [8*4096] in workspace.
// Runs once before the knn kernel. Also zeroes out[0].
// ---------------------------------------------------------------------------
__global__ __launch_bounds__(256) void soa_kernel(const float* __restrict__ pc,
                                                  float* __restrict__ xs,
                                                  float* __restrict__ ys,
                                                  float* __restrict__ zs,
                                                  float* __restrict__ out) {
  const int idx = blockIdx.x * 256 + threadIdx.x;  // 0..32767
  if (idx == 0) out[0] = 0.0f;
  const float x = pc[idx * 3 + 0];
  const float y = pc[idx * 3 + 1];
  const float z = pc[idx * 3 + 2];
  xs[idx] = x;
  ys[idx] = y;
  zs[idx] = z;
}

// ---------------------------------------------------------------------------
// Kernel 1 (fast path): per-point mean 5-NN squared distance.
// grid = 512 blocks, block = 1024 threads (16 waves). LDS = merge buffer only
// (20 KB, 2 blocks/CU). Candidates streamed via SMEM (see scan_seg_sc).
// ---------------------------------------------------------------------------
__global__ __launch_bounds__(TPB) void knn_value_sc(const float* __restrict__ xs,
                                                    const float* __restrict__ ys,
                                                    const float* __restrict__ zs,
                                                    float* __restrict__ value) {
  __shared__ unsigned cand[NSEG][64][KSEL];  // 20 KB

  const int tid = threadIdx.x;
  const int pt  = tid & 63;
  const int seg = __builtin_amdgcn_readfirstlane(tid >> 6);  // wave-uniform
  const int b    = blockIdx.x >> 6;
  const int tile = blockIdx.x & 63;
  const int i    = tile * 64 + pt;

  const float* __restrict__ xb = xs + b * NPTS;
  const float* __restrict__ yb = ys + b * NPTS;
  const float* __restrict__ zb = zs + b * NPTS;

  const float xi = xb[i];
  const float yi = yb[i];
  const float zi = zb[i];

  unsigned m[KSEL];
#pragma unroll
  for (int k = 0; k < KSEL; ++k) m[k] = FINF;

  const int j0 = seg * SEGLEN;
  const float4* __restrict__ xs4 = (const float4*)(xb + j0);
  const float4* __restrict__ ys4 = (const float4*)(yb + j0);
  const float4* __restrict__ zs4 = (const float4*)(zb + j0);

  // Tile's own 64 indices all fall in segment tile>>2 (SEGLEN=256): only that
  // wave pays the self-exclusion compares.
  if (seg == (tile >> 2)) {
    scan_seg_sc<true>(xs4, ys4, zs4, j0, i, xi, yi, zi, m);
  } else {
    scan_seg_sc<false>(xs4, ys4, zs4, j0, i, xi, yi, zi, m);
  }

#pragma unroll
  for (int k = 0; k < KSEL; ++k) cand[seg][pt][k] = m[k];
  __syncthreads();

  // Tree-merge the 16 sorted lists per point: 8,4,2,1 pairwise merges.
  for (int st = 1; st < NSEG; st <<= 1) {
    const int pairs = NSEG / (2 * st);
    if (tid < pairs * 64) {
      const int q = tid >> 6;
      const int p = tid & 63;
      unsigned* A = &cand[2 * st * q][p][0];
      const unsigned* B = &cand[2 * st * q + st][p][0];
      unsigned mm[KSEL];
#pragma unroll
      for (int k = 0; k < KSEL; ++k) mm[k] = A[k];
#pragma unroll
      for (int k = 0; k < KSEL; ++k) {
        unsigned t = B[k];
#pragma unroll
        for (int u = 0; u < KSEL - 1; ++u) {
          const unsigned lo = umn(mm[u], t);
          t = umx(mm[u], t);
          mm[u] = lo;
        }
        mm[KSEL - 1] = umn(mm[KSEL - 1], t);
      }
#pragma unroll
      for (int k = 0; k < KSEL; ++k) A[k] = mm[k];
    }
    __syncthreads();
  }

  // Self excluded in-scan: mean of the 5 smallest, summed ascending.
  if (tid < 64) {
    float s5 = 0.f;
#pragma unroll
    for (int k = 0; k < KSEL; ++k) s5 += __uint_as_float(cand[0][tid][k]);
    value[b * NPTS + tile * 64 + tid] = s5 * 0.2f;
  }
}

// ---------------------------------------------------------------------------
// Fallback (ws too small for SoA): R1 kernel, LDS-staged candidates.
// ---------------------------------------------------------------------------
template <bool EXCL>
static __device__ __forceinline__ void scan_seg_l(const float* __restrict__ xs,
                                                  const float* __restrict__ ys,
                                                  const float* __restrict__ zs,
                                                  const int j0, const int i,
                                                  const v2f nx2, const v2f ny2, const v2f nz2,
                                                  unsigned m[KSEL]) {
#pragma unroll 4
  for (int jj = 0; jj < SEGLEN; jj += 4) {
    const float4 cx = *(const float4*)&xs[j0 + jj];
    const float4 cy = *(const float4*)&ys[j0 + jj];
    const float4 cz = *(const float4*)&zs[j0 + jj];

    const v2f cxAB = {cx.x, cx.y}, cxCD = {cx.z, cx.w};
    const v2f cyAB = {cy.x, cy.y}, cyCD = {cy.z, cy.w};
    const v2f czAB = {cz.x, cz.y}, czCD = {cz.z, cz.w};

    const v2f dx0 = pk_add(cxAB, nx2);
    const v2f dx1 = pk_add(cxCD, nx2);
    const v2f dy0 = pk_add(cyAB, ny2);
    const v2f dy1 = pk_add(cyCD, ny2);
    const v2f dz0 = pk_add(czAB, nz2);
    const v2f dz1 = pk_add(czCD, nz2);

    v2f d0 = pk_mul(dx0, dx0);
    v2f d1 = pk_mul(dx1, dx1);
    d0 = pk_fma(dy0, dy0, d0);
    d1 = pk_fma(dy1, dy1, d1);
    d0 = pk_fma(dz0, dz0, d0);
    d1 = pk_fma(dz1, dz1, d1);

    unsigned uA = __float_as_uint(d0.x);
    unsigned uB = __float_as_uint(d0.y);
    unsigned uC = __float_as_uint(d1.x);
    unsigned uD = __float_as_uint(d1.y);
    if (EXCL) {
      const int jb = j0 + jj;
      if (jb + 0 == i) uA = FINF;
      if (jb + 1 == i) uB = FINF;
      if (jb + 2 == i) uC = FINF;
      if (jb + 3 == i) uD = FINF;
    }

    insert2(m, uA, uB);
    insert2(m, uC, uD);
  }
}

__global__ __launch_bounds__(TPB) void knn_value_lds(const float* __restrict__ pc,
                                                     float* __restrict__ value,
                                                     float* __restrict__ out) {
  __shared__ union __align__(16) {
    struct { float xs[NPTS]; float ys[NPTS]; float zs[NPTS]; } s;  // 48 KB
    unsigned cand[NSEG][64][KSEL];                                 // 20 KB
  } sh;

  const int tid = threadIdx.x;
  const int pt  = tid & 63;
  const int seg = __builtin_amdgcn_readfirstlane(tid >> 6);
  const int b    = blockIdx.x >> 6;
  const int tile = blockIdx.x & 63;
  const int i    = tile * 64 + pt;

  if (blockIdx.x == 0 && tid == 0) out[0] = 0.0f;

  const float* __restrict__ base = pc + (size_t)b * (NPTS * 3);

#pragma unroll
  for (int p = 0; p < NPTS / TPB; ++p) {
    const int idx = tid + p * TPB;
    sh.s.xs[idx] = base[idx * 3 + 0];
    sh.s.ys[idx] = base[idx * 3 + 1];
    sh.s.zs[idx] = base[idx * 3 + 2];
  }
  __syncthreads();

  const float xi = sh.s.xs[i];
  const float yi = sh.s.ys[i];
  const float zi = sh.s.zs[i];
  const v2f nx2 = {-xi, -xi};
  const v2f ny2 = {-yi, -yi};
  const v2f nz2 = {-zi, -zi};

  unsigned m[KSEL];
#pragma unroll
  for (int k = 0; k < KSEL; ++k) m[k] = FINF;

  const int j0 = seg * SEGLEN;
  if (seg == (tile >> 2)) {
    scan_seg_l<true>(sh.s.xs, sh.s.ys, sh.s.zs, j0, i, nx2, ny2, nz2, m);
  } else {
    scan_seg_l<false>(sh.s.xs, sh.s.ys, sh.s.zs, j0, i, nx2, ny2, nz2, m);
  }
  __syncthreads();

#pragma unroll
  for (int k = 0; k < KSEL; ++k) sh.cand[seg][pt][k] = m[k];
  __syncthreads();

  for (int st = 1; st < NSEG; st <<= 1) {
    const int pairs = NSEG / (2 * st);
    if (tid < pairs * 64) {
      const int q = tid >> 6;
      const int p = tid & 63;
      unsigned* A = &sh.cand[2 * st * q][p][0];
      const unsigned* B = &sh.cand[2 * st * q + st][p][0];
      unsigned mm[KSEL];
#pragma unroll
      for (int k = 0; k < KSEL; ++k) mm[k] = A[k];
#pragma unroll
      for (int k = 0; k < KSEL; ++k) {
        unsigned t = B[k];
#pragma unroll
        for (int u = 0; u < KSEL - 1; ++u) {
          const unsigned lo = umn(mm[u], t);
          t = umx(mm[u], t);
          mm[u] = lo;
        }
        mm[KSEL - 1] = umn(mm[KSEL - 1], t);
      }
#pragma unroll
      for (int k = 0; k < KSEL; ++k) A[k] = mm[k];
    }
    __syncthreads();
  }

  if (tid < 64) {
    float s5 = 0.f;
#pragma unroll
    for (int k = 0; k < KSEL; ++k) s5 += __uint_as_float(sh.cand[0][tid][k]);
    value[b * NPTS + tile * 64 + tid] = s5 * 0.2f;
  }
}

// ---------------------------------------------------------------------------
// Kernel 2: per-batch stats + masked mean * weight -> atomicAdd into out.
// UNCHANGED (bit-exact output).
// ---------------------------------------------------------------------------
__global__ __launch_bounds__(256) void stats_kernel(const float* __restrict__ value,
                                                    const float* __restrict__ weights,
                                                    float* __restrict__ out) {
  __shared__ float red[256];
  const int b   = blockIdx.x;
  const int tid = threadIdx.x;
  const float* __restrict__ v = value + b * NPTS;

  float s = 0.f;
  for (int j = tid; j < NPTS; j += 256) s += v[j];
  red[tid] = s;
  __syncthreads();
  for (int off = 128; off > 0; off >>= 1) {
    if (tid < off) red[tid] += red[tid + off];
    __syncthreads();
  }
  const float mean = red[0] * (1.0f / NPTS);
  __syncthreads();

  float s2 = 0.f;
  for (int j = tid; j < NPTS; j += 256) {
    const float d = v[j] - mean;
    s2 += d * d;
  }
  red[tid] = s2;
  __syncthreads();
  for (int off = 128; off > 0; off >>= 1) {
    if (tid < off) red[tid] += red[tid + off];
    __syncthreads();
  }
  const float thr = mean + ALPHA * sqrtf(red[0] * (1.0f / (NPTS - 1)));
  __syncthreads();

  float s3 = 0.f;
  for (int j = tid; j < NPTS; j += 256) {
    const float vv = v[j];
    if (vv > thr) s3 += vv;
  }
  red[tid] = s3;
  __syncthreads();
  for (int off = 128; off > 0; off >>= 1) {
    if (tid < off) red[tid] += red[tid + off];
    __syncthreads();
  }
  if (tid == 0) {
    atomicAdd(out, red[0] * (1.0f / NPTS) * weights[b] * (1.0f / BATCH));
  }
}

extern "C" void kernel_launch(void* const* d_in, const int* in_sizes, int n_in,
                              void* d_out, int out_size, void* d_ws, size_t ws_size,
                              hipStream_t stream) {
  const float* pc      = (const float*)d_in[0];   // [8,4096,3] f32
  const float* weights = (const float*)d_in[1];   // [8] f32
  float* out   = (float*)d_out;                   // scalar f32
  float* wsf   = (float*)d_ws;

  const size_t NB = (size_t)BATCH * NPTS;         // 32768
  const size_t need = NB * 4 * sizeof(float);     // value + xs + ys + zs = 512 KB

  if (ws_size >= need) {
    float* value = wsf;
    float* xs = wsf + NB;
    float* ys = wsf + 2 * NB;
    float* zs = wsf + 3 * NB;
    soa_kernel<<<dim3(BATCH * NPTS / 256), dim3(256), 0, stream>>>(pc, xs, ys, zs, out);
    knn_value_sc<<<dim3(BATCH * (NPTS / 64)), dim3(TPB), 0, stream>>>(xs, ys, zs, value);
    stats_kernel<<<dim3(BATCH), dim3(256), 0, stream>>>(value, weights, out);
  } else {
    float* value = wsf;                           // 128 KB (R1 layout)
    knn_value_lds<<<dim3(BATCH * (NPTS / 64)), dim3(TPB), 0, stream>>>(pc, value, out);
    stats_kernel<<<dim3(BATCH), dim3(256), 0, stream>>>(value, weights, out);
  }
}